// Round 10
// baseline (1134.246 us; speedup 1.0000x reference)
//
#include <hip/hip_runtime.h>

// ============================================================================
// TransformerSubsetAggregator on MI355X (gfx950) — round 10
// vs r9: k_ff and k_qkv widened to 1024-thread blocks (16 waves, 256 tokens),
// grid 256, __launch_bounds__(1024,8): 2 blocks/CU = 32 waves/CU (~100% occ,
// was 39%), halves per-block weight L2 streaming and barrier rounds/token.
// Register budget: cap 2048/8=256 unified >= 128 live (r7 spill lesson).
// Pipeline: k_prep | k_sel(+LN1->H1p) | k_qkv | k_attn | k_oproj(+LN2) |
//           k_ff(+pool->Fp) | memset(out) | k_headmlp
// ============================================================================

#define DIM   256
#define LSEQ  128
#define KTOK  8

typedef __bf16 bf16x8 __attribute__((ext_vector_type(8)));
typedef float  f32x4  __attribute__((ext_vector_type(4)));
typedef unsigned short u16x8 __attribute__((ext_vector_type(8)));

__device__ __forceinline__ f32x4 mfma16(bf16x8 a, bf16x8 b, f32x4 c) {
  // D[m][n] = sum_k A[m][k]B[n][k]; lane map (both ops): idx=lane&15,
  // k=(lane>>4)*8+j. D: col(lane&15)=n, row=(lane>>4)*4+reg=m.
  return __builtin_amdgcn_mfma_f32_16x16x32_bf16(a, b, c, 0, 0, 0);
}

__device__ __forceinline__ unsigned short f2bf(float f) {
  unsigned u = __float_as_uint(f);
  u = (u + 0x7FFFu + ((u >> 16) & 1u)) >> 16;   // RNE
  return (unsigned short)u;
}

__device__ __forceinline__ unsigned pack2bf(float a, float b) {
  return (unsigned)f2bf(a) | ((unsigned)f2bf(b) << 16);
}

// tanh-form gelu (~12 VALU ops); dev from exact ~1e-3 << bf16 rounding.
__device__ __forceinline__ float gelu_fast(float x) {
  const float y = 0.7978845608f * __builtin_fmaf(0.044715f * x * x, x, x);
  const float e = __expf(2.f * y);
  const float t = 1.f - 2.f * __builtin_amdgcn_rcpf(e + 1.f);
  return 0.5f * x * (1.f + t);
}

union U4 { unsigned u[4]; bf16x8 v; };

// ---- async global->LDS, 16B/lane; lds base wave-uniform, HW adds lane*16.
__device__ __forceinline__ void gload16(const unsigned short* g, unsigned short* lds_uniform) {
  auto gp = reinterpret_cast<const __attribute__((address_space(1))) unsigned*>(
      reinterpret_cast<uintptr_t>(g));
  auto lp = reinterpret_cast<__attribute__((address_space(3))) unsigned*>(
      (unsigned)reinterpret_cast<uintptr_t>(lds_uniform));
  __builtin_amdgcn_global_load_lds(gp, lp, 16, 0, 0);
}

// ---- 32KB chunk staging: register prefetch + LDS commit (512-thr k_oproj)
struct Stage32 { u16x8 r[4]; };
__device__ __forceinline__ void stage_load(Stage32& st, const unsigned short* __restrict__ g, int tid) {
  #pragma unroll
  for (int i = 0; i < 4; ++i) st.r[i] = *(const u16x8*)&g[(tid + i * 512) * 8];
}
__device__ __forceinline__ void stage_commit(const Stage32& st, unsigned short* l, int tid) {
  #pragma unroll
  for (int i = 0; i < 4; ++i) *(u16x8*)&l[(tid + i * 512) * 8] = st.r[i];
}

// ---------------------------------------------------------------------------
// k_prep: pack weights fp32 -> bf16 fragment-major.
// ---------------------------------------------------------------------------
__device__ __forceinline__ void pack_region(
    const float* __restrict__ src, unsigned short* __restrict__ dst,
    int g, int KC, int Ksrc, int Klim)
{
  const int ln = g & 63;
  const int t = g >> 6;
  const int s = t % KC;
  const int ntile = t / KC;
  const int row = ntile * 16 + (ln & 15);
  const int c0 = s * 32 + (ln >> 4) * 8;
  u16x8 o;
  #pragma unroll
  for (int j = 0; j < 8; ++j) {
    float val = (c0 + j < Klim) ? src[(long)row * Ksrc + c0 + j] : 0.f;
    o[j] = f2bf(val);
  }
  *(u16x8*)&dst[(long)g * 8] = o;
}

__device__ __forceinline__ void pack_region_kmaj(
    const float* __restrict__ src, unsigned short* __restrict__ dst,
    int g, int NT, int Ksrc)
{
  const int ln = g & 63;
  const int t = g >> 6;
  const int ntile = t % NT;
  const int s = t / NT;
  const int row = ntile * 16 + (ln & 15);
  const int c0 = s * 32 + (ln >> 4) * 8;
  u16x8 o;
  #pragma unroll
  for (int j = 0; j < 8; ++j) o[j] = f2bf(src[(long)row * Ksrc + c0 + j]);
  *(u16x8*)&dst[(long)g * 8] = o;
}

#define PREP_GROUPS 172032
__global__ __launch_bounds__(256) void k_prep(
    const float* __restrict__ wqkv, const float* __restrict__ wo,
    const float* __restrict__ wff1, const float* __restrict__ wff2,
    const float* __restrict__ wout1, const float* __restrict__ wout2,
    unsigned short* __restrict__ oq, unsigned short* __restrict__ oo,
    unsigned short* __restrict__ of1, unsigned short* __restrict__ of2,
    unsigned short* __restrict__ oo1, unsigned short* __restrict__ oo2)
{
  int g = blockIdx.x * 256 + threadIdx.x;
  if (g < 24576) { pack_region(wqkv, oq, g, 8, 256, 256); return; }     // n-major
  g -= 24576;
  if (g < 8192)  { pack_region(wo, oo, g, 8, 256, 256); return; }       // n-major
  g -= 8192;
  if (g < 32768) { pack_region(wff1, of1, g, 8, 256, 256); return; }    // n-major (f-chunked)
  g -= 32768;
  if (g < 32768) { pack_region_kmaj(wff2, of2, g, 16, 1024); return; }  // k-major
  g -= 32768;
  if (g < 40960) { pack_region(wout1, oo1, g, 10, 257, 257); return; }  // n-major (f-chunked)
  g -= 40960;
  if (g < 32768) { pack_region_kmaj(wout2, oo2, g, 16, 1024); }         // k-major
}

// ---------------------------------------------------------------------------
// k_sel: top-8 (lax.top_k ties: value desc, idx asc), sort picked idx asc,
// gather v + pos_embed -> X fp32 (row-major), fused LN1 -> H1 PACKED bf16.
// ---------------------------------------------------------------------------
__global__ __launch_bounds__(256) void k_sel(
    const float* __restrict__ v, const int* __restrict__ batch_idx,
    const int* __restrict__ mask, const float* __restrict__ rank_scores,
    const float* __restrict__ pos_embed,
    const float* __restrict__ ln1g, const float* __restrict__ ln1b,
    float* __restrict__ X, unsigned short* __restrict__ H1p,
    int* __restrict__ NPICK)
{
  const int c = blockIdx.x;
  const int tid = threadIdx.x;
  __shared__ int s_mem[KTOK];
  __shared__ int s_np;

  if (tid < 64) {
    const int l = tid;
    unsigned long long key[2];
    #pragma unroll
    for (int t = 0; t < 2; ++t) {
      int p = l + 64 * t;
      int mk = mask[c * LSEQ + p];
      float s = rank_scores[c * LSEQ + p];
      unsigned u = __float_as_uint(s);
      u = (u & 0x80000000u) ? ~u : (u | 0x80000000u);
      unsigned long long kk =
          ((unsigned long long)u << 32) | (unsigned long long)(0xFFFFFFFFu - (unsigned)p);
      key[t] = mk ? kk : 0ull;
    }
    int w[KTOK];
    #pragma unroll
    for (int r = 0; r < KTOK; ++r) w[r] = 0x7FFFFFFF;
    int np = 0;
    for (int r = 0; r < KTOK; ++r) {
      unsigned long long best = key[0] > key[1] ? key[0] : key[1];
      for (int off = 32; off > 0; off >>= 1) {
        unsigned long long o = __shfl_xor(best, off, 64);
        if (o > best) best = o;
      }
      if (best == 0ull) break;
      int idx = (int)(0xFFFFFFFFu - (unsigned)(best & 0xFFFFFFFFull));
      w[np++] = idx;
      if (key[0] == best) key[0] = 0ull;
      if (key[1] == best) key[1] = 0ull;
    }
    #pragma unroll
    for (int a = 0; a < KTOK - 1; ++a)
      #pragma unroll
      for (int b2 = 0; b2 < KTOK - 1 - a; ++b2) {
        int x0 = w[b2], x1 = w[b2 + 1];
        w[b2] = min(x0, x1); w[b2 + 1] = max(x0, x1);
      }
    if (l < KTOK) s_mem[l] = (l < np) ? batch_idx[c * LSEQ + w[l]] : -1;
    if (l == 0) { s_np = np; NPICK[c] = np; }
  }
  __syncthreads();

  const int np = s_np;
  const int j = tid >> 5, q = tid & 31;     // 32 threads/token, 8 cols each
  const int r = s_mem[j];
  const float4* v4  = (const float4*)v;
  const float4* pe4 = (const float4*)pos_embed;
  float4* X4 = (float4*)X;

  float4 xv[2];                              // cols q*8 .. q*8+7
  #pragma unroll
  for (int rep = 0; rep < 2; ++rep) {
    const int f = 2 * q + rep;
    float4 pe = pe4[j * 64 + f];
    float4 val = make_float4(0.f, 0.f, 0.f, 0.f);
    if (j < np) val = v4[(long)r * 64 + f];
    xv[rep].x = val.x + pe.x; xv[rep].y = val.y + pe.y;
    xv[rep].z = val.z + pe.z; xv[rep].w = val.w + pe.w;
    X4[((long)c * KTOK + j) * 64 + f] = xv[rep];
  }
  float sum = 0.f, ss = 0.f;
  #pragma unroll
  for (int rep = 0; rep < 2; ++rep) {
    sum += xv[rep].x + xv[rep].y + xv[rep].z + xv[rep].w;
    ss  += xv[rep].x * xv[rep].x + xv[rep].y * xv[rep].y
         + xv[rep].z * xv[rep].z + xv[rep].w * xv[rep].w;
  }
  #pragma unroll
  for (int off = 1; off <= 16; off <<= 1) {
    sum += __shfl_xor(sum, off); ss += __shfl_xor(ss, off);
  }
  const float mu = sum * (1.f / 256.f);
  const float var = ss * (1.f / 256.f) - mu * mu;
  const float rstd = rsqrtf(var + 1e-5f);
  const int t = c * KTOK + j;
  const int mtile = t >> 4, lr = t & 15;
  const int s = q >> 2, lq = q & 3;
  u16x8 o;
  const int col = q * 8;
  o[0] = f2bf((xv[0].x - mu) * rstd * ln1g[col + 0] + ln1b[col + 0]);
  o[1] = f2bf((xv[0].y - mu) * rstd * ln1g[col + 1] + ln1b[col + 1]);
  o[2] = f2bf((xv[0].z - mu) * rstd * ln1g[col + 2] + ln1b[col + 2]);
  o[3] = f2bf((xv[0].w - mu) * rstd * ln1g[col + 3] + ln1b[col + 3]);
  o[4] = f2bf((xv[1].x - mu) * rstd * ln1g[col + 4] + ln1b[col + 4]);
  o[5] = f2bf((xv[1].y - mu) * rstd * ln1g[col + 5] + ln1b[col + 5]);
  o[6] = f2bf((xv[1].z - mu) * rstd * ln1g[col + 6] + ln1b[col + 6]);
  o[7] = f2bf((xv[1].w - mu) * rstd * ln1g[col + 7] + ln1b[col + 7]);
  *(u16x8*)&H1p[((long)(mtile * 8 + s) * 64 + lq * 16 + lr) * 8] = o;
}

// ---------------------------------------------------------------------------
// k_qkv: QKV GEMM, M=65536, N=768, K=256. 1024 thr = 16 waves = 256 tokens.
// 2 blocks/CU = 32 waves/CU; weight stream halved vs 512-thr version.
// D-frag -> per-wave LDS transpose -> coalesced 16B/lane row-major stores.
// ---------------------------------------------------------------------------
__global__ __launch_bounds__(1024, 8) void k_qkv(
    const unsigned short* __restrict__ H1p, unsigned short* __restrict__ QKVp,
    const unsigned short* __restrict__ wqp, const float* __restrict__ bqkv)
{
  __shared__ unsigned short buf[16384];       // 32 KB
  __shared__ unsigned short sT[16 * 16 * 72]; // 36.9 KB: per-wave transpose
  const int tid = threadIdx.x;
  const int wv = tid >> 6, ln = tid & 63;
  const int lr = ln & 15, lq = ln >> 4;
  const int mtile = blockIdx.x * 16 + wv;
  const f32x4 vzero = {0.f, 0.f, 0.f, 0.f};
  unsigned short* sTw = &sT[wv * 1152];

  bf16x8 af[8];
  #pragma unroll
  for (int s = 0; s < 8; ++s)
    af[s] = *(const bf16x8*)&H1p[((long)(mtile * 8 + s) * 64 + ln) * 8];

  u16x8 st0 = *(const u16x8*)&wqp[tid * 8];
  u16x8 st1 = *(const u16x8*)&wqp[(tid + 1024) * 8];
  for (int c = 0; c < 12; ++c) {
    *(u16x8*)&buf[tid * 8] = st0;
    *(u16x8*)&buf[(tid + 1024) * 8] = st1;
    __syncthreads();
    if (c < 11) {
      st0 = *(const u16x8*)&wqp[(c + 1) * 16384 + tid * 8];
      st1 = *(const u16x8*)&wqp[(c + 1) * 16384 + (tid + 1024) * 8];
    }
    f32x4 acc[4];
    #pragma unroll
    for (int nt = 0; nt < 4; ++nt) acc[nt] = vzero;
    #pragma unroll
    for (int s = 0; s < 8; ++s) {
      #pragma unroll
      for (int nt = 0; nt < 4; ++nt) {
        bf16x8 b = *(const bf16x8*)&buf[(nt * 8 + s) * 512 + ln * 8];
        acc[nt] = mfma16(af[s], b, acc[nt]);
      }
    }
    #pragma unroll
    for (int nt = 0; nt < 4; ++nt) {
      const float bias = bqkv[c * 64 + nt * 16 + lr];
      #pragma unroll
      for (int reg = 0; reg < 4; ++reg)
        sTw[(lq * 4 + reg) * 72 + nt * 16 + lr] = f2bf(acc[nt][reg] + bias);
    }
    const int r8 = ln >> 3, cg = ln & 7;
    #pragma unroll
    for (int h = 0; h < 2; ++h) {
      const int tok = h * 8 + r8;
      u16x8 vv = *(const u16x8*)&sTw[tok * 72 + cg * 8];
      *(u16x8*)&QKVp[((long)(mtile * 16 + tok)) * 768 + c * 64 + cg * 8] = vv;
    }
    __syncthreads();
  }
}

// ---------------------------------------------------------------------------
// k_attn: 4 chains (32 tokens)/block, 128 threads (all active: c x hh x qi);
// stage QKV tile, softmax-attention, write O in PACKED A-fragment layout.
// ---------------------------------------------------------------------------
#define SQV 776   // 768 + 8

__global__ __launch_bounds__(128) void k_attn(
    const unsigned short* __restrict__ QKVp, const int* __restrict__ NPICK,
    unsigned short* __restrict__ Op)
{
  __shared__ unsigned short sQKV[32 * SQV];
  __shared__ int s_np[4];
  const int tid = threadIdx.x;
  const int blk = blockIdx.x;
  if (tid < 4) s_np[tid] = NPICK[blk * 4 + tid];
  for (int i = tid; i < 3072; i += 128) {
    const int r = i / 96, u = i - r * 96;
    *(u16x8*)&sQKV[r * SQV + u * 8] =
        *(const u16x8*)&QKVp[((long)blk * 32 + r) * 768 + u * 8];
  }
  __syncthreads();

  const int c = tid >> 5, hh = (tid >> 3) & 3, qi = tid & 7;
  const int natt = max(1, s_np[c]);
  const int qrow = c * 8 + qi;
  float sc[8];
  #pragma unroll
  for (int j = 0; j < 8; ++j) sc[j] = -1e30f;
  for (int j = 0; j < natt; ++j) {
    float d = 0.f;
    #pragma unroll
    for (int dc = 0; dc < 8; ++dc) {
      bf16x8 qv = *(const bf16x8*)&sQKV[qrow * SQV + hh * 64 + dc * 8];
      bf16x8 kv = *(const bf16x8*)&sQKV[(c * 8 + j) * SQV + 256 + hh * 64 + dc * 8];
      #pragma unroll
      for (int e = 0; e < 8; ++e) d += (float)qv[e] * (float)kv[e];
    }
    sc[j] = d * 0.125f;
  }
  float mx = -1e30f;
  #pragma unroll
  for (int j = 0; j < 8; ++j) mx = fmaxf(mx, sc[j]);
  float pr[8]; float ssum = 0.f;
  #pragma unroll
  for (int j = 0; j < 8; ++j) {
    float e = (j < natt) ? __expf(sc[j] - mx) : 0.f;
    pr[j] = e; ssum += e;
  }
  const float inv = 1.f / ssum;
  const int t = blk * 32 + qrow;
  const int mt = t >> 4, lrt = t & 15;
  #pragma unroll
  for (int dc = 0; dc < 8; ++dc) {
    float o8[8] = {0.f,0.f,0.f,0.f,0.f,0.f,0.f,0.f};
    for (int j = 0; j < natt; ++j) {
      const float pj = pr[j] * inv;
      bf16x8 vv = *(const bf16x8*)&sQKV[(c * 8 + j) * SQV + 512 + hh * 64 + dc * 8];
      #pragma unroll
      for (int e = 0; e < 8; ++e) o8[e] += pj * (float)vv[e];
    }
    u16x8 o;
    #pragma unroll
    for (int e = 0; e < 8; ++e) o[e] = f2bf(o8[e]);
    const int s = hh * 2 + (dc >> 2), lqt = dc & 3;
    *(u16x8*)&Op[((long)(mt * 8 + s) * 64 + lqt * 16 + lrt) * 8] = o;
  }
}

// ---------------------------------------------------------------------------
// k_oproj: X += O @ wo^T + bo, FUSED LN2 -> H2p. Each wave owns 16 full rows:
// accumulate sum/ss during the residual store, shfl-reduce over the 4 lanes
// per row, re-read L1-hot X, write packed H2p.
// ---------------------------------------------------------------------------
__global__ __launch_bounds__(512, 4) void k_oproj(
    const unsigned short* __restrict__ Op, float* __restrict__ X,
    const unsigned short* __restrict__ wop, const float* __restrict__ bo,
    const float* __restrict__ ln2g, const float* __restrict__ ln2b,
    unsigned short* __restrict__ H2p)
{
  __shared__ unsigned short buf[16384];
  __shared__ float sTf[8 * 16 * 68];         // per-wave 16 tok x 64 col (+4 pad)
  const int tid = threadIdx.x;
  const int wv = tid >> 6, ln = tid & 63;
  const int lr = ln & 15, lq = ln >> 4;
  const int mtile = blockIdx.x * 8 + wv;
  const f32x4 vzero = {0.f, 0.f, 0.f, 0.f};
  float* sTw = &sTf[wv * 1088];

  bf16x8 af[8];
  #pragma unroll
  for (int s = 0; s < 8; ++s)
    af[s] = *(const bf16x8*)&Op[((long)(mtile * 8 + s) * 64 + ln) * 8];

  const int r4 = ln >> 2, g4 = ln & 3;
  float lsum = 0.f, lss = 0.f;               // partial LN sums for row r4

  Stage32 st;
  stage_load(st, wop, tid);
  for (int c = 0; c < 4; ++c) {
    stage_commit(st, buf, tid);
    __syncthreads();
    if (c < 3) stage_load(st, wop + (c + 1) * 16384, tid);
    f32x4 acc[4];
    #pragma unroll
    for (int nt = 0; nt < 4; ++nt) acc[nt] = vzero;
    #pragma unroll
    for (int s = 0; s < 8; ++s) {
      #pragma unroll
      for (int nt = 0; nt < 4; ++nt) {
        bf16x8 b = *(const bf16x8*)&buf[(nt * 8 + s) * 512 + ln * 8];
        acc[nt] = mfma16(af[s], b, acc[nt]);
      }
    }
    #pragma unroll
    for (int nt = 0; nt < 4; ++nt) {
      const float bias = bo[c * 64 + nt * 16 + lr];
      #pragma unroll
      for (int reg = 0; reg < 4; ++reg)
        sTw[(lq * 4 + reg) * 68 + nt * 16 + lr] = acc[nt][reg] + bias;
    }
    #pragma unroll
    for (int it = 0; it < 4; ++it) {
      const int gi = it * 4 + g4;
      f32x4 vv = *(const f32x4*)&sTw[r4 * 68 + gi * 4];
      float4* xp = (float4*)&X[((long)(mtile * 16 + r4)) * DIM + c * 64 + gi * 4];
      float4 old = *xp;
      old.x += vv[0]; old.y += vv[1]; old.z += vv[2]; old.w += vv[3];
      *xp = old;
      lsum += old.x + old.y + old.z + old.w;
      lss  += old.x * old.x + old.y * old.y + old.z * old.z + old.w * old.w;
    }
    __syncthreads();
  }
  // ---- fused LN2: lanes 4*r4..4*r4+3 hold partials of row r4 ----
  lsum += __shfl_xor(lsum, 1); lss += __shfl_xor(lss, 1);
  lsum += __shfl_xor(lsum, 2); lss += __shfl_xor(lss, 2);
  const float mu = lsum * (1.f / 256.f);
  const float rstd = rsqrtf(lss * (1.f / 256.f) - mu * mu + 1e-5f);
  const int row = mtile * 16 + r4;
  #pragma unroll
  for (int i = 0; i < 8; ++i) {
    const int q = i * 4 + g4;                // col-group 0..31
    const float4 x0 = *(const float4*)&X[(long)row * DIM + q * 8];
    const float4 x1 = *(const float4*)&X[(long)row * DIM + q * 8 + 4];
    const float4 g0 = *(const float4*)&ln2g[q * 8];
    const float4 g1 = *(const float4*)&ln2g[q * 8 + 4];
    const float4 b0 = *(const float4*)&ln2b[q * 8];
    const float4 b1 = *(const float4*)&ln2b[q * 8 + 4];
    u16x8 o;
    o[0] = f2bf((x0.x - mu) * rstd * g0.x + b0.x);
    o[1] = f2bf((x0.y - mu) * rstd * g0.y + b0.y);
    o[2] = f2bf((x0.z - mu) * rstd * g0.z + b0.z);
    o[3] = f2bf((x0.w - mu) * rstd * g0.w + b0.w);
    o[4] = f2bf((x1.x - mu) * rstd * g1.x + b1.x);
    o[5] = f2bf((x1.y - mu) * rstd * g1.y + b1.y);
    o[6] = f2bf((x1.z - mu) * rstd * g1.z + b1.z);
    o[7] = f2bf((x1.w - mu) * rstd * g1.w + b1.w);
    *(u16x8*)&H2p[((long)(mtile * 8 + (q >> 2)) * 64 + (q & 3) * 16 + r4) * 8] = o;
  }
}

// ---------------------------------------------------------------------------
// k_ff: pooled = meanpool(x + gelu(h2@wff1^T+b1)@wff2^T+b2) FUSED.
// 1024 thr = 16 waves = 256 tokens/block; 2 blocks/CU = 32 waves/CU.
// FF1 operand-swapped; FF2 A-frags via quad shfl exchange; weights via
// global_load_lds. Epilogue: masked pool + 1/np + scatter to Fp.
// ---------------------------------------------------------------------------
__global__ __launch_bounds__(1024, 8) void k_ff(
    const float* __restrict__ X, const unsigned short* __restrict__ H2p,
    const unsigned short* __restrict__ w1p, const unsigned short* __restrict__ w2p,
    const float* __restrict__ bff1, const float* __restrict__ bff2,
    const int* __restrict__ NPICK, const float* __restrict__ count,
    unsigned short* __restrict__ Fp)
{
  __shared__ unsigned short bufA[16384];   // 32 KB: w1[f]
  __shared__ unsigned short bufB[16384];   // 32 KB: w2[f]
  const int tid = threadIdx.x;
  const int wv = tid >> 6, ln = tid & 63;
  const int lr = ln & 15, lq = ln >> 4;
  const int mtile = blockIdx.x * 16 + wv;
  const f32x4 vzero = {0.f, 0.f, 0.f, 0.f};

  f32x4 acc3[16];
  #pragma unroll
  for (int nt = 0; nt < 16; ++nt) acc3[nt] = vzero;

  const int laneA = ((lq & 1) * 2) * 16 + lr;   // src lanes for quad exchange
  const int laneB = laneA + 16;
  const bool hi = (lq & 2) != 0;                // needs nt tile 2*s2+1

  for (int f = 0; f < 16; ++f) {
    __syncthreads();                       // all waves done reading prev chunk
    // async stage 64KB: wave-uniform LDS base + lane*16B (2 issues per buffer)
    #pragma unroll
    for (int i = 0; i < 2; ++i) {
      const int off = (i * 1024 + wv * 64) * 8;
      gload16(w1p + (long)f * 16384 + off + ln * 8, &bufA[off]);
      gload16(w2p + (long)f * 16384 + off + ln * 8, &bufB[off]);
    }
    __syncthreads();                       // barrier drains vmcnt -> LDS ready

    // FF1 swapped: D[m=ffcol][n=token]; A-frag (H2p) re-read, L1-hot
    f32x4 ga[4];
    #pragma unroll
    for (int nt = 0; nt < 4; ++nt) ga[nt] = vzero;
    #pragma unroll
    for (int s = 0; s < 8; ++s) {
      const bf16x8 afs = *(const bf16x8*)&H2p[((long)(mtile * 8 + s) * 64 + ln) * 8];
      #pragma unroll
      for (int nt = 0; nt < 4; ++nt) {
        bf16x8 w1f = *(const bf16x8*)&bufA[(nt * 8 + s) * 512 + ln * 8];
        ga[nt] = mfma16(w1f, afs, ga[nt]);
      }
    }
    unsigned p0[4], p1[4];
    #pragma unroll
    for (int nt = 0; nt < 4; ++nt) {
      const float4 b4 = *(const float4*)&bff1[f * 64 + nt * 16 + lq * 4];
      const float g0 = gelu_fast(ga[nt][0] + b4.x);
      const float g1 = gelu_fast(ga[nt][1] + b4.y);
      const float g2 = gelu_fast(ga[nt][2] + b4.z);
      const float g3 = gelu_fast(ga[nt][3] + b4.w);
      p0[nt] = pack2bf(g0, g1);
      p1[nt] = pack2bf(g2, g3);
    }
    #pragma unroll
    for (int s2 = 0; s2 < 2; ++s2) {
      const unsigned a0 = (unsigned)__shfl((int)p0[2 * s2],     laneA, 64);
      const unsigned a1 = (unsigned)__shfl((int)p1[2 * s2],     laneA, 64);
      const unsigned a2 = (unsigned)__shfl((int)p0[2 * s2],     laneB, 64);
      const unsigned a3 = (unsigned)__shfl((int)p1[2 * s2],     laneB, 64);
      const unsigned c0 = (unsigned)__shfl((int)p0[2 * s2 + 1], laneA, 64);
      const unsigned c1 = (unsigned)__shfl((int)p1[2 * s2 + 1], laneA, 64);
      const unsigned c2 = (unsigned)__shfl((int)p0[2 * s2 + 1], laneB, 64);
      const unsigned c3 = (unsigned)__shfl((int)p1[2 * s2 + 1], laneB, 64);
      U4 uu;
      uu.u[0] = hi ? c0 : a0; uu.u[1] = hi ? c1 : a1;
      uu.u[2] = hi ? c2 : a2; uu.u[3] = hi ? c3 : a3;
      const bf16x8 gfrag = uu.v;
      #pragma unroll
      for (int nt = 0; nt < 16; ++nt) {
        bf16x8 w2f = *(const bf16x8*)&bufB[(s2 * 16 + nt) * 512 + ln * 8];
        acc3[nt] = mfma16(gfrag, w2f, acc3[nt]);
      }
    }
  }

  // ---- epilogue: final x = X + acc3 + bias; masked pool per chain ----
  // wave owns tokens mtile*16..+15 = chains mtile*2 (rows 0-7), mtile*2+1 (8-15)
  const int chain0 = mtile * 2;
  const int npc = NPICK[chain0 + (lq >> 1)];   // this lane's rows' chain
  float psum[16];
  #pragma unroll
  for (int nt = 0; nt < 16; ++nt) {
    const int col = nt * 16 + lr;
    const float bias = bff2[col];
    float ps = 0.f;
    #pragma unroll
    for (int reg = 0; reg < 4; ++reg) {
      const int row = lq * 4 + reg;
      const float val = X[((long)mtile * 16 + row) * DIM + col] + acc3[nt][reg] + bias;
      if ((row & 7) < npc) ps += val;
    }
    psum[nt] = ps;
  }
  const float inv = (npc > 0) ? (1.f / (float)npc) : 0.f;
  #pragma unroll
  for (int nt = 0; nt < 16; ++nt) {
    psum[nt] += __shfl_xor(psum[nt], 16);      // combine lq-pair (same chain)
    psum[nt] *= inv;
  }
  if ((lq & 1) == 0) {
    // lq==0 -> chain0, lq==2 -> chain1: write pooled cols (16 each)
    const int ch = chain0 + (lq >> 1);
    const int rtile = ch >> 4, lrf = ch & 15;
    #pragma unroll
    for (int nt = 0; nt < 16; ++nt) {
      const int col = nt * 16 + lr;
      const int s = col >> 5, lqf = (col >> 3) & 3, j = col & 7;
      Fp[((long)(rtile * 10 + s) * 64 + lqf * 16 + lrf) * 8 + j] = f2bf(psum[nt]);
    }
  } else if (lr < 8) {
    // lq==1 -> chain0, lq==3 -> chain1: tail cols 256..319 (groups q=32..39)
    const int ch = chain0 + (lq >> 1);
    const int rtile = ch >> 4, lrf = ch & 15;
    const int q = 32 + lr;
    const int s = q >> 2, lqf = q & 3;
    u16x8 o = {0,0,0,0,0,0,0,0};
    if (q == 32) o[0] = f2bf(log1pf(count[ch]));
    *(u16x8*)&Fp[((long)(rtile * 10 + s) * 64 + lqf * 16 + lrf) * 8] = o;
  }
}

// ---------------------------------------------------------------------------
// k_headmlp: out += FF-quarter partial of gelu(F@wout1^T+b1)@wout2^T
// (+ bout2 from quarter 0). Operand-swap + shfl exchange; staging via
// global_load_lds. LDS 72KB -> 2 blocks/CU.
// ---------------------------------------------------------------------------
__global__ __launch_bounds__(512, 4) void k_headmlp(
    const unsigned short* __restrict__ Fp,
    const unsigned short* __restrict__ wo1p, const unsigned short* __restrict__ wo2p,
    const float* __restrict__ bout1, const float* __restrict__ bout2,
    float* __restrict__ out)
{
  __shared__ unsigned short bufA[20480];   // 40 KB: wout1 f-chunk
  __shared__ unsigned short bufB[16384];   // 32 KB: wout2 f-chunk
  const int tid = threadIdx.x;
  const int fq = blockIdx.x & 3;
  const int mchunk = blockIdx.x >> 2;
  const int wv = tid >> 6, ln = tid & 63;
  const int lr = ln & 15, lq = ln >> 4;
  const int rtile = mchunk * 8 + wv;
  const f32x4 vzero = {0.f, 0.f, 0.f, 0.f};

  f32x4 oacc[16];
  #pragma unroll
  for (int nt = 0; nt < 16; ++nt) oacc[nt] = vzero;

  const int laneA = ((lq & 1) * 2) * 16 + lr;
  const int laneB = laneA + 16;
  const bool hi = (lq & 2) != 0;

  for (int it = 0; it < 4; ++it) {
    const int f = fq * 4 + it;
    __syncthreads();                         // previous iter's reads done
    #pragma unroll
    for (int i = 0; i < 5; ++i) {
      const int off = (i * 512 + wv * 64) * 8;
      gload16(wo1p + (long)f * 20480 + off + ln * 8, &bufA[off]);
    }
    #pragma unroll
    for (int i = 0; i < 4; ++i) {
      const int off = (i * 512 + wv * 64) * 8;
      gload16(wo2p + (long)f * 16384 + off + ln * 8, &bufB[off]);
    }
    __syncthreads();

    f32x4 ga[4];
    #pragma unroll
    for (int nt = 0; nt < 4; ++nt) ga[nt] = vzero;
    #pragma unroll
    for (int s = 0; s < 10; ++s) {
      const bf16x8 afs = *(const bf16x8*)&Fp[((long)(rtile * 10 + s) * 64 + ln) * 8];
      #pragma unroll
      for (int nt = 0; nt < 4; ++nt) {
        bf16x8 w1f = *(const bf16x8*)&bufA[(nt * 10 + s) * 512 + ln * 8];
        ga[nt] = mfma16(w1f, afs, ga[nt]);
      }
    }
    unsigned p0[4], p1[4];
    #pragma unroll
    for (int nt = 0; nt < 4; ++nt) {
      const float4 b4 = *(const float4*)&bout1[f * 64 + nt * 16 + lq * 4];
      const float g0 = gelu_fast(ga[nt][0] + b4.x);
      const float g1 = gelu_fast(ga[nt][1] + b4.y);
      const float g2 = gelu_fast(ga[nt][2] + b4.z);
      const float g3 = gelu_fast(ga[nt][3] + b4.w);
      p0[nt] = pack2bf(g0, g1);
      p1[nt] = pack2bf(g2, g3);
    }
    #pragma unroll
    for (int s2 = 0; s2 < 2; ++s2) {
      const unsigned a0 = (unsigned)__shfl((int)p0[2 * s2],     laneA, 64);
      const unsigned a1 = (unsigned)__shfl((int)p1[2 * s2],     laneA, 64);
      const unsigned a2 = (unsigned)__shfl((int)p0[2 * s2],     laneB, 64);
      const unsigned a3 = (unsigned)__shfl((int)p1[2 * s2],     laneB, 64);
      const unsigned c0 = (unsigned)__shfl((int)p0[2 * s2 + 1], laneA, 64);
      const unsigned c1 = (unsigned)__shfl((int)p1[2 * s2 + 1], laneA, 64);
      const unsigned c2 = (unsigned)__shfl((int)p0[2 * s2 + 1], laneB, 64);
      const unsigned c3 = (unsigned)__shfl((int)p1[2 * s2 + 1], laneB, 64);
      U4 uu;
      uu.u[0] = hi ? c0 : a0; uu.u[1] = hi ? c1 : a1;
      uu.u[2] = hi ? c2 : a2; uu.u[3] = hi ? c3 : a3;
      const bf16x8 gfrag = uu.v;
      #pragma unroll
      for (int nt = 0; nt < 16; ++nt) {
        bf16x8 w2f = *(const bf16x8*)&bufB[(s2 * 16 + nt) * 512 + ln * 8];
        oacc[nt] = mfma16(gfrag, w2f, oacc[nt]);
      }
    }
  }
  #pragma unroll
  for (int nt = 0; nt < 16; ++nt) {
    const int col = nt * 16 + lr;
    const float bias = (fq == 0) ? bout2[col] : 0.f;
    #pragma unroll
    for (int reg = 0; reg < 4; ++reg) {
      const int row = mchunk * 128 + wv * 16 + lq * 4 + reg;
      atomicAdd(&out[(long)row * DIM + col], oacc[nt][reg] + bias);
    }
  }
}

// ---------------------------------------------------------------------------
extern "C" void kernel_launch(void* const* d_in, const int* in_sizes, int n_in,
                              void* d_out, int out_size, void* d_ws, size_t ws_size,
                              hipStream_t stream) {
  (void)in_sizes; (void)n_in; (void)out_size; (void)ws_size;
  const float* v          = (const float*)d_in[0];
  const int*   batch_idx  = (const int*)  d_in[1];
  const int*   mask       = (const int*)  d_in[2];
  const float* count      = (const float*)d_in[3];
  const float* rank       = (const float*)d_in[4];
  const float* pe         = (const float*)d_in[5];
  const float* w_qkv      = (const float*)d_in[6];
  const float* b_qkv      = (const float*)d_in[7];
  const float* w_o        = (const float*)d_in[8];
  const float* b_o        = (const float*)d_in[9];
  const float* ln1g       = (const float*)d_in[10];
  const float* ln1b       = (const float*)d_in[11];
  const float* ln2g       = (const float*)d_in[12];
  const float* ln2b       = (const float*)d_in[13];
  const float* w_ff1      = (const float*)d_in[14];
  const float* b_ff1      = (const float*)d_in[15];
  const float* w_ff2      = (const float*)d_in[16];
  const float* b_ff2      = (const float*)d_in[17];
  const float* w_out1     = (const float*)d_in[18];
  const float* b_out1     = (const float*)d_in[19];
  const float* w_out2     = (const float*)d_in[20];
  const float* b_out2     = (const float*)d_in[21];
  float* out = (float*)d_out;

  char* ws = (char*)d_ws;
  float*          X     = (float*)ws;                              // 67,108,864
  unsigned short* H1p   = (unsigned short*)(ws + 67108864);        // 33,554,432
  unsigned short* Op    = H1p;                                     // alias: H1p dead after k_qkv
  unsigned short* QKVp  = (unsigned short*)(ws + 100663296);       // 100,663,296 (65536x768 bf16)
  unsigned short* H2p   = QKVp;                                    // alias: QKVp dead after k_attn
  unsigned short* Fp    = (unsigned short*)(ws + 134217728);       // alias inside QKVp region
  int*            NPICK = (int*)(ws + 201326592);                  //     32,768
  unsigned short* wq_bf   = (unsigned short*)(ws + 201359360);     //    393,216
  unsigned short* wo_bf   = (unsigned short*)(ws + 201752576);     //    131,072
  unsigned short* wff1_bf = (unsigned short*)(ws + 201883648);     //    524,288
  unsigned short* wff2_bf = (unsigned short*)(ws + 202407936);     //    524,288 (k-major)
  unsigned short* wo1_bf  = (unsigned short*)(ws + 202932224);     //    655,360 (n-major, f-chunked)
  unsigned short* wo2_bf  = (unsigned short*)(ws + 203587584);     //    524,288 (k-major) -> end 204,111,872

  k_prep<<<PREP_GROUPS / 256, 256, 0, stream>>>(
      w_qkv, w_o, w_ff1, w_ff2, w_out1, w_out2,
      wq_bf, wo_bf, wff1_bf, wff2_bf, wo1_bf, wo2_bf);

  k_sel<<<8192, 256, 0, stream>>>(v, batch_idx, mask, rank, pe,
                                  ln1g, ln1b, X, H1p, NPICK);

  k_qkv<<<256, 1024, 0, stream>>>(H1p, QKVp, wq_bf, b_qkv);

  k_attn<<<2048, 128, 0, stream>>>(QKVp, NPICK, Op);

  k_oproj<<<512, 512, 0, stream>>>(Op, X, wo_bf, b_o, ln2g, ln2b, H2p);

  k_ff<<<256, 1024, 0, stream>>>(X, H2p, wff1_bf, wff2_bf, b_ff1, b_ff2,
                                 NPICK, count, Fp);

  hipMemsetAsync(out, 0, (size_t)8192 * 256 * sizeof(float), stream);

  k_headmlp<<<256, 512, 0, stream>>>(Fp, wo1_bf, wo2_bf, b_out1, b_out2, out);
}

// Round 11
// 530.147 us; speedup vs baseline: 2.1395x; 2.1395x over previous
//
#include <hip/hip_runtime.h>

// ============================================================================
// TransformerSubsetAggregator on MI355X (gfx950) — round 11
// vs r10: REVERT the 1024-thread widening (it triggered compiler register
// starvation: VGPR_Count 32, 3.2GB scratch traffic — same pathology as r7;
// empirically the only spill-free fast config is r9's 512-thr/(512,4)).
// k_qkv/k_ff restored byte-identical to r9. One safe orthogonal change:
// k_attn stages only K+V (33.3KB LDS -> 4 blocks/CU, was 48.5KB/3) and reads
// per-thread Q slices directly from L2-warm QKVp into registers.
// Pipeline: k_prep | k_sel(+LN1->H1p) | k_qkv | k_attn | k_oproj(+LN2) |
//           k_ff(+pool->Fp) | memset(out) | k_headmlp
// ============================================================================

#define DIM   256
#define LSEQ  128
#define KTOK  8

typedef __bf16 bf16x8 __attribute__((ext_vector_type(8)));
typedef float  f32x4  __attribute__((ext_vector_type(4)));
typedef unsigned short u16x8 __attribute__((ext_vector_type(8)));

__device__ __forceinline__ f32x4 mfma16(bf16x8 a, bf16x8 b, f32x4 c) {
  // D[m][n] = sum_k A[m][k]B[n][k]; lane map (both ops): idx=lane&15,
  // k=(lane>>4)*8+j. D: col(lane&15)=n, row=(lane>>4)*4+reg=m.
  return __builtin_amdgcn_mfma_f32_16x16x32_bf16(a, b, c, 0, 0, 0);
}

__device__ __forceinline__ unsigned short f2bf(float f) {
  unsigned u = __float_as_uint(f);
  u = (u + 0x7FFFu + ((u >> 16) & 1u)) >> 16;   // RNE
  return (unsigned short)u;
}

__device__ __forceinline__ unsigned pack2bf(float a, float b) {
  return (unsigned)f2bf(a) | ((unsigned)f2bf(b) << 16);
}

// tanh-form gelu (~12 VALU ops); dev from exact ~1e-3 << bf16 rounding.
__device__ __forceinline__ float gelu_fast(float x) {
  const float y = 0.7978845608f * __builtin_fmaf(0.044715f * x * x, x, x);
  const float e = __expf(2.f * y);
  const float t = 1.f - 2.f * __builtin_amdgcn_rcpf(e + 1.f);
  return 0.5f * x * (1.f + t);
}

union U4 { unsigned u[4]; bf16x8 v; };

// ---- async global->LDS, 16B/lane; lds base wave-uniform, HW adds lane*16.
__device__ __forceinline__ void gload16(const unsigned short* g, unsigned short* lds_uniform) {
  auto gp = reinterpret_cast<const __attribute__((address_space(1))) unsigned*>(
      reinterpret_cast<uintptr_t>(g));
  auto lp = reinterpret_cast<__attribute__((address_space(3))) unsigned*>(
      (unsigned)reinterpret_cast<uintptr_t>(lds_uniform));
  __builtin_amdgcn_global_load_lds(gp, lp, 16, 0, 0);
}

// ---- 32KB chunk staging: register prefetch + LDS commit (512-thr kernels)
struct Stage32 { u16x8 r[4]; };
__device__ __forceinline__ void stage_load(Stage32& st, const unsigned short* __restrict__ g, int tid) {
  #pragma unroll
  for (int i = 0; i < 4; ++i) st.r[i] = *(const u16x8*)&g[(tid + i * 512) * 8];
}
__device__ __forceinline__ void stage_commit(const Stage32& st, unsigned short* l, int tid) {
  #pragma unroll
  for (int i = 0; i < 4; ++i) *(u16x8*)&l[(tid + i * 512) * 8] = st.r[i];
}

// ---------------------------------------------------------------------------
// k_prep: pack weights fp32 -> bf16 fragment-major.
// ---------------------------------------------------------------------------
__device__ __forceinline__ void pack_region(
    const float* __restrict__ src, unsigned short* __restrict__ dst,
    int g, int KC, int Ksrc, int Klim)
{
  const int ln = g & 63;
  const int t = g >> 6;
  const int s = t % KC;
  const int ntile = t / KC;
  const int row = ntile * 16 + (ln & 15);
  const int c0 = s * 32 + (ln >> 4) * 8;
  u16x8 o;
  #pragma unroll
  for (int j = 0; j < 8; ++j) {
    float val = (c0 + j < Klim) ? src[(long)row * Ksrc + c0 + j] : 0.f;
    o[j] = f2bf(val);
  }
  *(u16x8*)&dst[(long)g * 8] = o;
}

__device__ __forceinline__ void pack_region_kmaj(
    const float* __restrict__ src, unsigned short* __restrict__ dst,
    int g, int NT, int Ksrc)
{
  const int ln = g & 63;
  const int t = g >> 6;
  const int ntile = t % NT;
  const int s = t / NT;
  const int row = ntile * 16 + (ln & 15);
  const int c0 = s * 32 + (ln >> 4) * 8;
  u16x8 o;
  #pragma unroll
  for (int j = 0; j < 8; ++j) o[j] = f2bf(src[(long)row * Ksrc + c0 + j]);
  *(u16x8*)&dst[(long)g * 8] = o;
}

#define PREP_GROUPS 172032
__global__ __launch_bounds__(256) void k_prep(
    const float* __restrict__ wqkv, const float* __restrict__ wo,
    const float* __restrict__ wff1, const float* __restrict__ wff2,
    const float* __restrict__ wout1, const float* __restrict__ wout2,
    unsigned short* __restrict__ oq, unsigned short* __restrict__ oo,
    unsigned short* __restrict__ of1, unsigned short* __restrict__ of2,
    unsigned short* __restrict__ oo1, unsigned short* __restrict__ oo2)
{
  int g = blockIdx.x * 256 + threadIdx.x;
  if (g < 24576) { pack_region(wqkv, oq, g, 8, 256, 256); return; }     // n-major
  g -= 24576;
  if (g < 8192)  { pack_region(wo, oo, g, 8, 256, 256); return; }       // n-major
  g -= 8192;
  if (g < 32768) { pack_region(wff1, of1, g, 8, 256, 256); return; }    // n-major (f-chunked)
  g -= 32768;
  if (g < 32768) { pack_region_kmaj(wff2, of2, g, 16, 1024); return; }  // k-major
  g -= 32768;
  if (g < 40960) { pack_region(wout1, oo1, g, 10, 257, 257); return; }  // n-major (f-chunked)
  g -= 40960;
  if (g < 32768) { pack_region_kmaj(wout2, oo2, g, 16, 1024); }         // k-major
}

// ---------------------------------------------------------------------------
// k_sel: top-8 (lax.top_k ties: value desc, idx asc), sort picked idx asc,
// gather v + pos_embed -> X fp32 (row-major), fused LN1 -> H1 PACKED bf16.
// ---------------------------------------------------------------------------
__global__ __launch_bounds__(256) void k_sel(
    const float* __restrict__ v, const int* __restrict__ batch_idx,
    const int* __restrict__ mask, const float* __restrict__ rank_scores,
    const float* __restrict__ pos_embed,
    const float* __restrict__ ln1g, const float* __restrict__ ln1b,
    float* __restrict__ X, unsigned short* __restrict__ H1p,
    int* __restrict__ NPICK)
{
  const int c = blockIdx.x;
  const int tid = threadIdx.x;
  __shared__ int s_mem[KTOK];
  __shared__ int s_np;

  if (tid < 64) {
    const int l = tid;
    unsigned long long key[2];
    #pragma unroll
    for (int t = 0; t < 2; ++t) {
      int p = l + 64 * t;
      int mk = mask[c * LSEQ + p];
      float s = rank_scores[c * LSEQ + p];
      unsigned u = __float_as_uint(s);
      u = (u & 0x80000000u) ? ~u : (u | 0x80000000u);
      unsigned long long kk =
          ((unsigned long long)u << 32) | (unsigned long long)(0xFFFFFFFFu - (unsigned)p);
      key[t] = mk ? kk : 0ull;
    }
    int w[KTOK];
    #pragma unroll
    for (int r = 0; r < KTOK; ++r) w[r] = 0x7FFFFFFF;
    int np = 0;
    for (int r = 0; r < KTOK; ++r) {
      unsigned long long best = key[0] > key[1] ? key[0] : key[1];
      for (int off = 32; off > 0; off >>= 1) {
        unsigned long long o = __shfl_xor(best, off, 64);
        if (o > best) best = o;
      }
      if (best == 0ull) break;
      int idx = (int)(0xFFFFFFFFu - (unsigned)(best & 0xFFFFFFFFull));
      w[np++] = idx;
      if (key[0] == best) key[0] = 0ull;
      if (key[1] == best) key[1] = 0ull;
    }
    #pragma unroll
    for (int a = 0; a < KTOK - 1; ++a)
      #pragma unroll
      for (int b2 = 0; b2 < KTOK - 1 - a; ++b2) {
        int x0 = w[b2], x1 = w[b2 + 1];
        w[b2] = min(x0, x1); w[b2 + 1] = max(x0, x1);
      }
    if (l < KTOK) s_mem[l] = (l < np) ? batch_idx[c * LSEQ + w[l]] : -1;
    if (l == 0) { s_np = np; NPICK[c] = np; }
  }
  __syncthreads();

  const int np = s_np;
  const int j = tid >> 5, q = tid & 31;     // 32 threads/token, 8 cols each
  const int r = s_mem[j];
  const float4* v4  = (const float4*)v;
  const float4* pe4 = (const float4*)pos_embed;
  float4* X4 = (float4*)X;

  float4 xv[2];                              // cols q*8 .. q*8+7
  #pragma unroll
  for (int rep = 0; rep < 2; ++rep) {
    const int f = 2 * q + rep;
    float4 pe = pe4[j * 64 + f];
    float4 val = make_float4(0.f, 0.f, 0.f, 0.f);
    if (j < np) val = v4[(long)r * 64 + f];
    xv[rep].x = val.x + pe.x; xv[rep].y = val.y + pe.y;
    xv[rep].z = val.z + pe.z; xv[rep].w = val.w + pe.w;
    X4[((long)c * KTOK + j) * 64 + f] = xv[rep];
  }
  float sum = 0.f, ss = 0.f;
  #pragma unroll
  for (int rep = 0; rep < 2; ++rep) {
    sum += xv[rep].x + xv[rep].y + xv[rep].z + xv[rep].w;
    ss  += xv[rep].x * xv[rep].x + xv[rep].y * xv[rep].y
         + xv[rep].z * xv[rep].z + xv[rep].w * xv[rep].w;
  }
  #pragma unroll
  for (int off = 1; off <= 16; off <<= 1) {
    sum += __shfl_xor(sum, off); ss += __shfl_xor(ss, off);
  }
  const float mu = sum * (1.f / 256.f);
  const float var = ss * (1.f / 256.f) - mu * mu;
  const float rstd = rsqrtf(var + 1e-5f);
  const int t = c * KTOK + j;
  const int mtile = t >> 4, lr = t & 15;
  const int s = q >> 2, lq = q & 3;
  u16x8 o;
  const int col = q * 8;
  o[0] = f2bf((xv[0].x - mu) * rstd * ln1g[col + 0] + ln1b[col + 0]);
  o[1] = f2bf((xv[0].y - mu) * rstd * ln1g[col + 1] + ln1b[col + 1]);
  o[2] = f2bf((xv[0].z - mu) * rstd * ln1g[col + 2] + ln1b[col + 2]);
  o[3] = f2bf((xv[0].w - mu) * rstd * ln1g[col + 3] + ln1b[col + 3]);
  o[4] = f2bf((xv[1].x - mu) * rstd * ln1g[col + 4] + ln1b[col + 4]);
  o[5] = f2bf((xv[1].y - mu) * rstd * ln1g[col + 5] + ln1b[col + 5]);
  o[6] = f2bf((xv[1].z - mu) * rstd * ln1g[col + 6] + ln1b[col + 6]);
  o[7] = f2bf((xv[1].w - mu) * rstd * ln1g[col + 7] + ln1b[col + 7]);
  *(u16x8*)&H1p[((long)(mtile * 8 + s) * 64 + lq * 16 + lr) * 8] = o;
}

// ---------------------------------------------------------------------------
// k_qkv: QKV GEMM, M=65536, N=768, K=256. 512 thr = 8 waves = 128 tokens.
// (r9 config — do not touch: r7/r10 launch-bound changes both spilled.)
// ---------------------------------------------------------------------------
__global__ __launch_bounds__(512, 4) void k_qkv(
    const unsigned short* __restrict__ H1p, unsigned short* __restrict__ QKVp,
    const unsigned short* __restrict__ wqp, const float* __restrict__ bqkv)
{
  __shared__ unsigned short buf[16384];      // 32 KB
  __shared__ unsigned short sT[8 * 16 * 72]; // per-wave 16 tok x 64 col (+8 pad)
  const int tid = threadIdx.x;
  const int wv = tid >> 6, ln = tid & 63;
  const int lr = ln & 15, lq = ln >> 4;
  const int mtile = blockIdx.x * 8 + wv;
  const f32x4 vzero = {0.f, 0.f, 0.f, 0.f};
  unsigned short* sTw = &sT[wv * 1152];

  bf16x8 af[8];
  #pragma unroll
  for (int s = 0; s < 8; ++s)
    af[s] = *(const bf16x8*)&H1p[((long)(mtile * 8 + s) * 64 + ln) * 8];

  Stage32 st;
  stage_load(st, wqp, tid);
  for (int c = 0; c < 12; ++c) {
    stage_commit(st, buf, tid);
    __syncthreads();
    if (c < 11) stage_load(st, wqp + (c + 1) * 16384, tid);
    f32x4 acc[4];
    #pragma unroll
    for (int nt = 0; nt < 4; ++nt) acc[nt] = vzero;
    #pragma unroll
    for (int s = 0; s < 8; ++s) {
      #pragma unroll
      for (int nt = 0; nt < 4; ++nt) {
        bf16x8 b = *(const bf16x8*)&buf[(nt * 8 + s) * 512 + ln * 8];
        acc[nt] = mfma16(af[s], b, acc[nt]);
      }
    }
    #pragma unroll
    for (int nt = 0; nt < 4; ++nt) {
      const float bias = bqkv[c * 64 + nt * 16 + lr];
      #pragma unroll
      for (int reg = 0; reg < 4; ++reg)
        sTw[(lq * 4 + reg) * 72 + nt * 16 + lr] = f2bf(acc[nt][reg] + bias);
    }
    const int r8 = ln >> 3, cg = ln & 7;
    #pragma unroll
    for (int h = 0; h < 2; ++h) {
      const int tok = h * 8 + r8;
      u16x8 vv = *(const u16x8*)&sTw[tok * 72 + cg * 8];
      *(u16x8*)&QKVp[((long)(mtile * 16 + tok)) * 768 + c * 64 + cg * 8] = vv;
    }
    __syncthreads();
  }
}

// ---------------------------------------------------------------------------
// k_attn: 4 chains (32 tokens)/block, 128 threads. Stages only K+V into LDS
// (33.3KB -> 4 blocks/CU, was 48.5KB/3); per-thread Q slice read directly
// from L2-warm QKVp into registers before the barrier.
// ---------------------------------------------------------------------------
#define SKV 520   // 512 + 8

__global__ __launch_bounds__(128) void k_attn(
    const unsigned short* __restrict__ QKVp, const int* __restrict__ NPICK,
    unsigned short* __restrict__ Op)
{
  __shared__ unsigned short sKV[32 * SKV];   // cols 0..255 = K, 256..511 = V
  __shared__ int s_np[4];
  const int tid = threadIdx.x;
  const int blk = blockIdx.x;
  if (tid < 4) s_np[tid] = NPICK[blk * 4 + tid];
  for (int i = tid; i < 2048; i += 128) {    // 16 x u16x8 per thread
    const int r = i >> 6, u = i & 63;
    *(u16x8*)&sKV[r * SKV + u * 8] =
        *(const u16x8*)&QKVp[((long)blk * 32 + r) * 768 + 256 + u * 8];
  }
  const int c = tid >> 5, hh = (tid >> 3) & 3, qi = tid & 7;
  const int qrow = c * 8 + qi;
  bf16x8 qv[8];                              // own Q slice: 128B from global
  #pragma unroll
  for (int dc = 0; dc < 8; ++dc)
    qv[dc] = *(const bf16x8*)&QKVp[((long)blk * 32 + qrow) * 768 + hh * 64 + dc * 8];
  __syncthreads();

  const int natt = max(1, s_np[c]);
  float sc[8];
  #pragma unroll
  for (int j = 0; j < 8; ++j) sc[j] = -1e30f;
  for (int j = 0; j < natt; ++j) {
    float d = 0.f;
    #pragma unroll
    for (int dc = 0; dc < 8; ++dc) {
      bf16x8 kv = *(const bf16x8*)&sKV[(c * 8 + j) * SKV + hh * 64 + dc * 8];
      #pragma unroll
      for (int e = 0; e < 8; ++e) d += (float)qv[dc][e] * (float)kv[e];
    }
    sc[j] = d * 0.125f;
  }
  float mx = -1e30f;
  #pragma unroll
  for (int j = 0; j < 8; ++j) mx = fmaxf(mx, sc[j]);
  float pr[8]; float ssum = 0.f;
  #pragma unroll
  for (int j = 0; j < 8; ++j) {
    float e = (j < natt) ? __expf(sc[j] - mx) : 0.f;
    pr[j] = e; ssum += e;
  }
  const float inv = 1.f / ssum;
  const int t = blk * 32 + qrow;
  const int mt = t >> 4, lrt = t & 15;
  #pragma unroll
  for (int dc = 0; dc < 8; ++dc) {
    float o8[8] = {0.f,0.f,0.f,0.f,0.f,0.f,0.f,0.f};
    for (int j = 0; j < natt; ++j) {
      const float pj = pr[j] * inv;
      bf16x8 vv = *(const bf16x8*)&sKV[(c * 8 + j) * SKV + 256 + hh * 64 + dc * 8];
      #pragma unroll
      for (int e = 0; e < 8; ++e) o8[e] += pj * (float)vv[e];
    }
    u16x8 o;
    #pragma unroll
    for (int e = 0; e < 8; ++e) o[e] = f2bf(o8[e]);
    const int s = hh * 2 + (dc >> 2), lqt = dc & 3;
    *(u16x8*)&Op[((long)(mt * 8 + s) * 64 + lqt * 16 + lrt) * 8] = o;
  }
}

// ---------------------------------------------------------------------------
// k_oproj: X += O @ wo^T + bo, FUSED LN2 -> H2p. (r9 config.)
// ---------------------------------------------------------------------------
__global__ __launch_bounds__(512, 4) void k_oproj(
    const unsigned short* __restrict__ Op, float* __restrict__ X,
    const unsigned short* __restrict__ wop, const float* __restrict__ bo,
    const float* __restrict__ ln2g, const float* __restrict__ ln2b,
    unsigned short* __restrict__ H2p)
{
  __shared__ unsigned short buf[16384];
  __shared__ float sTf[8 * 16 * 68];         // per-wave 16 tok x 64 col (+4 pad)
  const int tid = threadIdx.x;
  const int wv = tid >> 6, ln = tid & 63;
  const int lr = ln & 15, lq = ln >> 4;
  const int mtile = blockIdx.x * 8 + wv;
  const f32x4 vzero = {0.f, 0.f, 0.f, 0.f};
  float* sTw = &sTf[wv * 1088];

  bf16x8 af[8];
  #pragma unroll
  for (int s = 0; s < 8; ++s)
    af[s] = *(const bf16x8*)&Op[((long)(mtile * 8 + s) * 64 + ln) * 8];

  const int r4 = ln >> 2, g4 = ln & 3;
  float lsum = 0.f, lss = 0.f;               // partial LN sums for row r4

  Stage32 st;
  stage_load(st, wop, tid);
  for (int c = 0; c < 4; ++c) {
    stage_commit(st, buf, tid);
    __syncthreads();
    if (c < 3) stage_load(st, wop + (c + 1) * 16384, tid);
    f32x4 acc[4];
    #pragma unroll
    for (int nt = 0; nt < 4; ++nt) acc[nt] = vzero;
    #pragma unroll
    for (int s = 0; s < 8; ++s) {
      #pragma unroll
      for (int nt = 0; nt < 4; ++nt) {
        bf16x8 b = *(const bf16x8*)&buf[(nt * 8 + s) * 512 + ln * 8];
        acc[nt] = mfma16(af[s], b, acc[nt]);
      }
    }
    #pragma unroll
    for (int nt = 0; nt < 4; ++nt) {
      const float bias = bo[c * 64 + nt * 16 + lr];
      #pragma unroll
      for (int reg = 0; reg < 4; ++reg)
        sTw[(lq * 4 + reg) * 68 + nt * 16 + lr] = acc[nt][reg] + bias;
    }
    #pragma unroll
    for (int it = 0; it < 4; ++it) {
      const int gi = it * 4 + g4;
      f32x4 vv = *(const f32x4*)&sTw[r4 * 68 + gi * 4];
      float4* xp = (float4*)&X[((long)(mtile * 16 + r4)) * DIM + c * 64 + gi * 4];
      float4 old = *xp;
      old.x += vv[0]; old.y += vv[1]; old.z += vv[2]; old.w += vv[3];
      *xp = old;
      lsum += old.x + old.y + old.z + old.w;
      lss  += old.x * old.x + old.y * old.y + old.z * old.z + old.w * old.w;
    }
    __syncthreads();
  }
  // ---- fused LN2: lanes 4*r4..4*r4+3 hold partials of row r4 ----
  lsum += __shfl_xor(lsum, 1); lss += __shfl_xor(lss, 1);
  lsum += __shfl_xor(lsum, 2); lss += __shfl_xor(lss, 2);
  const float mu = lsum * (1.f / 256.f);
  const float rstd = rsqrtf(lss * (1.f / 256.f) - mu * mu + 1e-5f);
  const int row = mtile * 16 + r4;
  #pragma unroll
  for (int i = 0; i < 8; ++i) {
    const int q = i * 4 + g4;                // col-group 0..31
    const float4 x0 = *(const float4*)&X[(long)row * DIM + q * 8];
    const float4 x1 = *(const float4*)&X[(long)row * DIM + q * 8 + 4];
    const float4 g0 = *(const float4*)&ln2g[q * 8];
    const float4 g1 = *(const float4*)&ln2g[q * 8 + 4];
    const float4 b0 = *(const float4*)&ln2b[q * 8];
    const float4 b1 = *(const float4*)&ln2b[q * 8 + 4];
    u16x8 o;
    o[0] = f2bf((x0.x - mu) * rstd * g0.x + b0.x);
    o[1] = f2bf((x0.y - mu) * rstd * g0.y + b0.y);
    o[2] = f2bf((x0.z - mu) * rstd * g0.z + b0.z);
    o[3] = f2bf((x0.w - mu) * rstd * g0.w + b0.w);
    o[4] = f2bf((x1.x - mu) * rstd * g1.x + b1.x);
    o[5] = f2bf((x1.y - mu) * rstd * g1.y + b1.y);
    o[6] = f2bf((x1.z - mu) * rstd * g1.z + b1.z);
    o[7] = f2bf((x1.w - mu) * rstd * g1.w + b1.w);
    *(u16x8*)&H2p[((long)(mtile * 8 + (q >> 2)) * 64 + (q & 3) * 16 + r4) * 8] = o;
  }
}

// ---------------------------------------------------------------------------
// k_ff: pooled = meanpool(x + gelu(h2@wff1^T+b1)@wff2^T+b2) FUSED.
// (r9 config — 512 thr, (512,4), gload16 staging, de-hoisted A. Do not touch.)
// ---------------------------------------------------------------------------
__global__ __launch_bounds__(512, 4) void k_ff(
    const float* __restrict__ X, const unsigned short* __restrict__ H2p,
    const unsigned short* __restrict__ w1p, const unsigned short* __restrict__ w2p,
    const float* __restrict__ bff1, const float* __restrict__ bff2,
    const int* __restrict__ NPICK, const float* __restrict__ count,
    unsigned short* __restrict__ Fp)
{
  __shared__ unsigned short bufA[16384];   // 32 KB: w1[f]
  __shared__ unsigned short bufB[16384];   // 32 KB: w2[f]
  const int tid = threadIdx.x;
  const int wv = tid >> 6, ln = tid & 63;
  const int lr = ln & 15, lq = ln >> 4;
  const int mtile = blockIdx.x * 8 + wv;
  const f32x4 vzero = {0.f, 0.f, 0.f, 0.f};

  f32x4 acc3[16];
  #pragma unroll
  for (int nt = 0; nt < 16; ++nt) acc3[nt] = vzero;

  const int laneA = ((lq & 1) * 2) * 16 + lr;   // src lanes for quad exchange
  const int laneB = laneA + 16;
  const bool hi = (lq & 2) != 0;                // needs nt tile 2*s2+1

  for (int f = 0; f < 16; ++f) {
    __syncthreads();                       // all waves done reading prev chunk
    #pragma unroll
    for (int i = 0; i < 4; ++i) {
      const int off = (i * 512 + wv * 64) * 8;
      gload16(w1p + (long)f * 16384 + off + ln * 8, &bufA[off]);
      gload16(w2p + (long)f * 16384 + off + ln * 8, &bufB[off]);
    }
    __syncthreads();                       // barrier drains vmcnt -> LDS ready

    // FF1 swapped: D[m=ffcol][n=token]; A-frag (H2p) re-read, L1-hot
    f32x4 ga[4];
    #pragma unroll
    for (int nt = 0; nt < 4; ++nt) ga[nt] = vzero;
    #pragma unroll
    for (int s = 0; s < 8; ++s) {
      const bf16x8 afs = *(const bf16x8*)&H2p[((long)(mtile * 8 + s) * 64 + ln) * 8];
      #pragma unroll
      for (int nt = 0; nt < 4; ++nt) {
        bf16x8 w1f = *(const bf16x8*)&bufA[(nt * 8 + s) * 512 + ln * 8];
        ga[nt] = mfma16(w1f, afs, ga[nt]);
      }
    }
    unsigned p0[4], p1[4];
    #pragma unroll
    for (int nt = 0; nt < 4; ++nt) {
      const float4 b4 = *(const float4*)&bff1[f * 64 + nt * 16 + lq * 4];
      const float g0 = gelu_fast(ga[nt][0] + b4.x);
      const float g1 = gelu_fast(ga[nt][1] + b4.y);
      const float g2 = gelu_fast(ga[nt][2] + b4.z);
      const float g3 = gelu_fast(ga[nt][3] + b4.w);
      p0[nt] = pack2bf(g0, g1);
      p1[nt] = pack2bf(g2, g3);
    }
    #pragma unroll
    for (int s2 = 0; s2 < 2; ++s2) {
      const unsigned a0 = (unsigned)__shfl((int)p0[2 * s2],     laneA, 64);
      const unsigned a1 = (unsigned)__shfl((int)p1[2 * s2],     laneA, 64);
      const unsigned a2 = (unsigned)__shfl((int)p0[2 * s2],     laneB, 64);
      const unsigned a3 = (unsigned)__shfl((int)p1[2 * s2],     laneB, 64);
      const unsigned c0 = (unsigned)__shfl((int)p0[2 * s2 + 1], laneA, 64);
      const unsigned c1 = (unsigned)__shfl((int)p1[2 * s2 + 1], laneA, 64);
      const unsigned c2 = (unsigned)__shfl((int)p0[2 * s2 + 1], laneB, 64);
      const unsigned c3 = (unsigned)__shfl((int)p1[2 * s2 + 1], laneB, 64);
      U4 uu;
      uu.u[0] = hi ? c0 : a0; uu.u[1] = hi ? c1 : a1;
      uu.u[2] = hi ? c2 : a2; uu.u[3] = hi ? c3 : a3;
      const bf16x8 gfrag = uu.v;
      #pragma unroll
      for (int nt = 0; nt < 16; ++nt) {
        bf16x8 w2f = *(const bf16x8*)&bufB[(s2 * 16 + nt) * 512 + ln * 8];
        acc3[nt] = mfma16(gfrag, w2f, acc3[nt]);
      }
    }
  }

  // ---- epilogue: final x = X + acc3 + bias; masked pool per chain ----
  const int chain0 = mtile * 2;
  const int npc = NPICK[chain0 + (lq >> 1)];   // this lane's rows' chain
  float psum[16];
  #pragma unroll
  for (int nt = 0; nt < 16; ++nt) {
    const int col = nt * 16 + lr;
    const float bias = bff2[col];
    float ps = 0.f;
    #pragma unroll
    for (int reg = 0; reg < 4; ++reg) {
      const int row = lq * 4 + reg;
      const float val = X[((long)mtile * 16 + row) * DIM + col] + acc3[nt][reg] + bias;
      if ((row & 7) < npc) ps += val;
    }
    psum[nt] = ps;
  }
  const float inv = (npc > 0) ? (1.f / (float)npc) : 0.f;
  #pragma unroll
  for (int nt = 0; nt < 16; ++nt) {
    psum[nt] += __shfl_xor(psum[nt], 16);      // combine lq-pair (same chain)
    psum[nt] *= inv;
  }
  if ((lq & 1) == 0) {
    const int ch = chain0 + (lq >> 1);
    const int rtile = ch >> 4, lrf = ch & 15;
    #pragma unroll
    for (int nt = 0; nt < 16; ++nt) {
      const int col = nt * 16 + lr;
      const int s = col >> 5, lqf = (col >> 3) & 3, j = col & 7;
      Fp[((long)(rtile * 10 + s) * 64 + lqf * 16 + lrf) * 8 + j] = f2bf(psum[nt]);
    }
  } else if (lr < 8) {
    const int ch = chain0 + (lq >> 1);
    const int rtile = ch >> 4, lrf = ch & 15;
    const int q = 32 + lr;
    const int s = q >> 2, lqf = q & 3;
    u16x8 o = {0,0,0,0,0,0,0,0};
    if (q == 32) o[0] = f2bf(log1pf(count[ch]));
    *(u16x8*)&Fp[((long)(rtile * 10 + s) * 64 + lqf * 16 + lrf) * 8] = o;
  }
}

// ---------------------------------------------------------------------------
// k_headmlp: out += FF-quarter partial of gelu(F@wout1^T+b1)@wout2^T
// (+ bout2 from quarter 0). (r9 config.)
// ---------------------------------------------------------------------------
__global__ __launch_bounds__(512, 4) void k_headmlp(
    const unsigned short* __restrict__ Fp,
    const unsigned short* __restrict__ wo1p, const unsigned short* __restrict__ wo2p,
    const float* __restrict__ bout1, const float* __restrict__ bout2,
    float* __restrict__ out)
{
  __shared__ unsigned short bufA[20480];   // 40 KB: wout1 f-chunk
  __shared__ unsigned short bufB[16384];   // 32 KB: wout2 f-chunk
  const int tid = threadIdx.x;
  const int fq = blockIdx.x & 3;
  const int mchunk = blockIdx.x >> 2;
  const int wv = tid >> 6, ln = tid & 63;
  const int lr = ln & 15, lq = ln >> 4;
  const int rtile = mchunk * 8 + wv;
  const f32x4 vzero = {0.f, 0.f, 0.f, 0.f};

  f32x4 oacc[16];
  #pragma unroll
  for (int nt = 0; nt < 16; ++nt) oacc[nt] = vzero;

  const int laneA = ((lq & 1) * 2) * 16 + lr;
  const int laneB = laneA + 16;
  const bool hi = (lq & 2) != 0;

  for (int it = 0; it < 4; ++it) {
    const int f = fq * 4 + it;
    __syncthreads();                         // previous iter's reads done
    #pragma unroll
    for (int i = 0; i < 5; ++i) {
      const int off = (i * 512 + wv * 64) * 8;
      gload16(wo1p + (long)f * 20480 + off + ln * 8, &bufA[off]);
    }
    #pragma unroll
    for (int i = 0; i < 4; ++i) {
      const int off = (i * 512 + wv * 64) * 8;
      gload16(wo2p + (long)f * 16384 + off + ln * 8, &bufB[off]);
    }
    __syncthreads();

    f32x4 ga[4];
    #pragma unroll
    for (int nt = 0; nt < 4; ++nt) ga[nt] = vzero;
    #pragma unroll
    for (int s = 0; s < 10; ++s) {
      const bf16x8 afs = *(const bf16x8*)&Fp[((long)(rtile * 10 + s) * 64 + ln) * 8];
      #pragma unroll
      for (int nt = 0; nt < 4; ++nt) {
        bf16x8 w1f = *(const bf16x8*)&bufA[(nt * 10 + s) * 512 + ln * 8];
        ga[nt] = mfma16(w1f, afs, ga[nt]);
      }
    }
    unsigned p0[4], p1[4];
    #pragma unroll
    for (int nt = 0; nt < 4; ++nt) {
      const float4 b4 = *(const float4*)&bout1[f * 64 + nt * 16 + lq * 4];
      const float g0 = gelu_fast(ga[nt][0] + b4.x);
      const float g1 = gelu_fast(ga[nt][1] + b4.y);
      const float g2 = gelu_fast(ga[nt][2] + b4.z);
      const float g3 = gelu_fast(ga[nt][3] + b4.w);
      p0[nt] = pack2bf(g0, g1);
      p1[nt] = pack2bf(g2, g3);
    }
    #pragma unroll
    for (int s2 = 0; s2 < 2; ++s2) {
      const unsigned a0 = (unsigned)__shfl((int)p0[2 * s2],     laneA, 64);
      const unsigned a1 = (unsigned)__shfl((int)p1[2 * s2],     laneA, 64);
      const unsigned a2 = (unsigned)__shfl((int)p0[2 * s2],     laneB, 64);
      const unsigned a3 = (unsigned)__shfl((int)p1[2 * s2],     laneB, 64);
      const unsigned c0 = (unsigned)__shfl((int)p0[2 * s2 + 1], laneA, 64);
      const unsigned c1 = (unsigned)__shfl((int)p1[2 * s2 + 1], laneA, 64);
      const unsigned c2 = (unsigned)__shfl((int)p0[2 * s2 + 1], laneB, 64);
      const unsigned c3 = (unsigned)__shfl((int)p1[2 * s2 + 1], laneB, 64);
      U4 uu;
      uu.u[0] = hi ? c0 : a0; uu.u[1] = hi ? c1 : a1;
      uu.u[2] = hi ? c2 : a2; uu.u[3] = hi ? c3 : a3;
      const bf16x8 gfrag = uu.v;
      #pragma unroll
      for (int nt = 0; nt < 16; ++nt) {
        bf16x8 w2f = *(const bf16x8*)&bufB[(s2 * 16 + nt) * 512 + ln * 8];
        oacc[nt] = mfma16(gfrag, w2f, oacc[nt]);
      }
    }
  }
  #pragma unroll
  for (int nt = 0; nt < 16; ++nt) {
    const int col = nt * 16 + lr;
    const float bias = (fq == 0) ? bout2[col] : 0.f;
    #pragma unroll
    for (int reg = 0; reg < 4; ++reg) {
      const int row = mchunk * 128 + wv * 16 + lq * 4 + reg;
      atomicAdd(&out[(long)row * DIM + col], oacc[nt][reg] + bias);
    }
  }
}

// ---------------------------------------------------------------------------
extern "C" void kernel_launch(void* const* d_in, const int* in_sizes, int n_in,
                              void* d_out, int out_size, void* d_ws, size_t ws_size,
                              hipStream_t stream) {
  (void)in_sizes; (void)n_in; (void)out_size; (void)ws_size;
  const float* v          = (const float*)d_in[0];
  const int*   batch_idx  = (const int*)  d_in[1];
  const int*   mask       = (const int*)  d_in[2];
  const float* count      = (const float*)d_in[3];
  const float* rank       = (const float*)d_in[4];
  const float* pe         = (const float*)d_in[5];
  const float* w_qkv      = (const float*)d_in[6];
  const float* b_qkv      = (const float*)d_in[7];
  const float* w_o        = (const float*)d_in[8];
  const float* b_o        = (const float*)d_in[9];
  const float* ln1g       = (const float*)d_in[10];
  const float* ln1b       = (const float*)d_in[11];
  const float* ln2g       = (const float*)d_in[12];
  const float* ln2b       = (const float*)d_in[13];
  const float* w_ff1      = (const float*)d_in[14];
  const float* b_ff1      = (const float*)d_in[15];
  const float* w_ff2      = (const float*)d_in[16];
  const float* b_ff2      = (const float*)d_in[17];
  const float* w_out1     = (const float*)d_in[18];
  const float* b_out1     = (const float*)d_in[19];
  const float* w_out2     = (const float*)d_in[20];
  const float* b_out2     = (const float*)d_in[21];
  float* out = (float*)d_out;

  char* ws = (char*)d_ws;
  float*          X     = (float*)ws;                              // 67,108,864
  unsigned short* H1p   = (unsigned short*)(ws + 67108864);        // 33,554,432
  unsigned short* Op    = H1p;                                     // alias: H1p dead after k_qkv
  unsigned short* QKVp  = (unsigned short*)(ws + 100663296);       // 100,663,296 (65536x768 bf16)
  unsigned short* H2p   = QKVp;                                    // alias: QKVp dead after k_attn
  unsigned short* Fp    = (unsigned short*)(ws + 134217728);       // alias inside QKVp region
  int*            NPICK = (int*)(ws + 201326592);                  //     32,768
  unsigned short* wq_bf   = (unsigned short*)(ws + 201359360);     //    393,216
  unsigned short* wo_bf   = (unsigned short*)(ws + 201752576);     //    131,072
  unsigned short* wff1_bf = (unsigned short*)(ws + 201883648);     //    524,288
  unsigned short* wff2_bf = (unsigned short*)(ws + 202407936);     //    524,288 (k-major)
  unsigned short* wo1_bf  = (unsigned short*)(ws + 202932224);     //    655,360 (n-major, f-chunked)
  unsigned short* wo2_bf  = (unsigned short*)(ws + 203587584);     //    524,288 (k-major) -> end 204,111,872

  k_prep<<<PREP_GROUPS / 256, 256, 0, stream>>>(
      w_qkv, w_o, w_ff1, w_ff2, w_out1, w_out2,
      wq_bf, wo_bf, wff1_bf, wff2_bf, wo1_bf, wo2_bf);

  k_sel<<<8192, 256, 0, stream>>>(v, batch_idx, mask, rank, pe,
                                  ln1g, ln1b, X, H1p, NPICK);

  k_qkv<<<512, 512, 0, stream>>>(H1p, QKVp, wq_bf, b_qkv);

  k_attn<<<2048, 128, 0, stream>>>(QKVp, NPICK, Op);

  k_oproj<<<512, 512, 0, stream>>>(Op, X, wo_bf, b_o, ln2g, ln2b, H2p);

  k_ff<<<512, 512, 0, stream>>>(X, H2p, wff1_bf, wff2_bf, b_ff1, b_ff2,
                                NPICK, count, Fp);

  hipMemsetAsync(out, 0, (size_t)8192 * 256 * sizeof(float), stream);

  k_headmlp<<<256, 512, 0, stream>>>(Fp, wo1_bf, wo2_bf, b_out1, b_out2, out);
}